// Round 11
// baseline (163.602 us; speedup 1.0000x reference)
//
#include <hip/hip_runtime.h>

#define TDIM   1024          // TOKEN_DIM
#define HID    256           // HIDDEN
#define FDIM   63            // 3*(2*10+1)
#define INDIM  1087          // TDIM + FDIM
#define TT     512           // T
#define NBATCH 2             // B
#define NROWS  1024          // B*T unique rows
#define KSPLIT 4             // k-split factor for stage1
#define KCHUNK 272           // ceil(1087/4) rounded to mult of 4
#define EPS_LN   1e-5f
#define EPS_NORM 1e-12f

// acc (float4) += s * w (float4)
#define FMA4(A, s, W)                                   \
    (A).x = fmaf((s), (W).x, (A).x);                    \
    (A).y = fmaf((s), (W).y, (A).y);                    \
    (A).z = fmaf((s), (W).z, (A).z);                    \
    (A).w = fmaf((s), (W).w, (A).w)

__device__ __forceinline__ float wave_reduce_sum(float v) {
    #pragma unroll
    for (int m = 32; m >= 1; m >>= 1) v += __shfl_xor(v, m);
    return v;
}

// fourier feature u (0..62) of a row: [x, sin(x*2^0..2^9), cos(x*2^0..2^9)] per coord
__device__ __forceinline__ float fourier_val(const float* __restrict__ anchors, int row, int u) {
    const int c = u / 21;
    const int w = u % 21;
    const float x = anchors[row * 3 + c];
    if (w == 0)  return x;
    if (w <= 10) return sinf(x * (float)(1u << (w - 1)));
    return cosf(x * (float)(1u << (w - 11)));
}

// ============================================================================
// S1: partial stage-1 GEMM (no LDS, no barriers in main loop).
// grid = 64 rowtiles(16 rows) x KSPLIT = 256 blocks, block = 512 threads
// (8 waves -> 2 waves/SIMD: one wave's FMA burst hides the other's loads).
// wave w owns rows rowbase+2w..+1 (wave-uniform -> broadcast token loads);
// lane owns cols c4..c4+3 (float4 W1 loads, 1KB/wave coalesced).
// part[z][row][col] = sum over k in chunk z of combined[row][k]*W1[k][col].
// ============================================================================
__global__ __launch_bounds__(512) void stage1_partial_kernel(
    const float* __restrict__ tokens,   // (1024,1024)
    const float* __restrict__ anchors,  // (1024,3)
    const float* __restrict__ W1,       // (1087,256)
    float* __restrict__ part)           // (KSPLIT,1024,256)
{
    const int tid    = threadIdx.x;
    const int rt     = blockIdx.x >> 2;        // 0..63 rowtile
    const int z      = blockIdx.x & 3;         // k-split index
    const int kstart = z * KCHUNK;
    const int kcount = min(KCHUNK, INDIM - kstart);   // 272 or 271
    const int wave   = tid >> 6;               // 0..7
    const int c4     = (tid & 63) << 2;        // col 0,4,..,252
    const int row0   = rt * 16 + wave * 2;     // first of this wave's 2 rows

    const float* __restrict__ t0p = tokens + (size_t)(row0 + 0) * TDIM;
    const float* __restrict__ t1p = tokens + (size_t)(row0 + 1) * TDIM;

    float4 acc0 = {0.f, 0.f, 0.f, 0.f};
    float4 acc1 = acc0;

    const int glim = kcount >> 2;                                   // 4k groups
    const int gtok = (kstart < TDIM) ? min(glim, (TDIM - kstart) >> 2) : 0;  // pure-token groups
    // gtok: z=0..2 -> 68 (=glim); z=3 -> 52.  Both divisible by 4 (clean unroll).

    // ---- token region: wave-uniform float4 token loads + float4 W1 loads ----
    #pragma unroll 4
    for (int g = 0; g < gtok; ++g) {
        const int k = kstart + (g << 2);
        const float4 w0 = *(const float4*)&W1[(size_t)(k + 0) * HID + c4];
        const float4 w1 = *(const float4*)&W1[(size_t)(k + 1) * HID + c4];
        const float4 w2 = *(const float4*)&W1[(size_t)(k + 2) * HID + c4];
        const float4 w3 = *(const float4*)&W1[(size_t)(k + 3) * HID + c4];
        const float4 s0 = *(const float4*)&t0p[k];
        const float4 s1 = *(const float4*)&t1p[k];
        FMA4(acc0, s0.x, w0); FMA4(acc0, s0.y, w1); FMA4(acc0, s0.z, w2); FMA4(acc0, s0.w, w3);
        FMA4(acc1, s1.x, w0); FMA4(acc1, s1.y, w1); FMA4(acc1, s1.z, w2); FMA4(acc1, s1.w, w3);
    }

    // ---- fourier region (k >= 1024): only the last k-chunk has these ----
    for (int g = gtok; g < glim; ++g) {
        const int k = kstart + (g << 2);       // k >= 1024 here (4-aligned)
        const float4 w0 = *(const float4*)&W1[(size_t)(k + 0) * HID + c4];
        const float4 w1 = *(const float4*)&W1[(size_t)(k + 1) * HID + c4];
        const float4 w2 = *(const float4*)&W1[(size_t)(k + 2) * HID + c4];
        const float4 w3 = *(const float4*)&W1[(size_t)(k + 3) * HID + c4];
        const int u = k - TDIM;
        float4 s0, s1;
        s0.x = fourier_val(anchors, row0 + 0, u);     s0.y = fourier_val(anchors, row0 + 0, u + 1);
        s0.z = fourier_val(anchors, row0 + 0, u + 2); s0.w = fourier_val(anchors, row0 + 0, u + 3);
        s1.x = fourier_val(anchors, row0 + 1, u);     s1.y = fourier_val(anchors, row0 + 1, u + 1);
        s1.z = fourier_val(anchors, row0 + 1, u + 2); s1.w = fourier_val(anchors, row0 + 1, u + 3);
        FMA4(acc0, s0.x, w0); FMA4(acc0, s0.y, w1); FMA4(acc0, s0.z, w2); FMA4(acc0, s0.w, w3);
        FMA4(acc1, s1.x, w0); FMA4(acc1, s1.y, w1); FMA4(acc1, s1.z, w2); FMA4(acc1, s1.w, w3);
    }

    // ---- scalar k tail (only last chunk: k = 1084..1086) ----
    for (int k = kstart + (glim << 2); k < kstart + kcount; ++k) {
        const float4 w = *(const float4*)&W1[(size_t)k * HID + c4];
        const float v0 = (k < TDIM) ? t0p[k] : fourier_val(anchors, row0 + 0, k - TDIM);
        const float v1 = (k < TDIM) ? t1p[k] : fourier_val(anchors, row0 + 1, k - TDIM);
        FMA4(acc0, v0, w); FMA4(acc1, v1, w);
    }

    float* __restrict__ pb = part + (size_t)z * NROWS * HID;
    *(float4*)&pb[(size_t)(row0 + 0) * HID + c4] = acc0;
    *(float4*)&pb[(size_t)(row0 + 1) * HID + c4] = acc1;
}

// ============================================================================
// S2: fused (bias + k-split reduce) -> LN1+ReLU -> stage2 GEMM -> LN2+ReLU
//     -> stage3 -> postprocess.  grid = 256 blocks x 256 threads, 4 rows/block.
// Stage2: wave = row (uniform b128 h1 broadcasts), lane = 4 cols (float4 W2).
// ============================================================================
__global__ __launch_bounds__(256) void decode_tail_kernel(
    const float* __restrict__ part,     // (KSPLIT,1024,256)
    const float* __restrict__ b1,
    const float* __restrict__ g1,
    const float* __restrict__ be1,
    const float* __restrict__ W2,       // (256,256)
    const float* __restrict__ b2,
    const float* __restrict__ g2,
    const float* __restrict__ be2,
    const float* __restrict__ W3,       // (256,14)
    const float* __restrict__ b3,       // (14)
    float* __restrict__ decoded)        // (1024,14)
{
    __shared__ float h1[4][HID];
    __shared__ float h2[4][HID];
    __shared__ float raws[4][16];

    const int tid  = threadIdx.x;
    const int wave = tid >> 6;
    const int lane = tid & 63;
    const int row  = blockIdx.x * 4 + wave;

    // ---- fused bias + partial reduce + LN1 + ReLU (wave per row) ----
    {
        const size_t off = (size_t)row * HID;
        float x0 = b1[lane], x1 = b1[lane + 64], x2 = b1[lane + 128], x3 = b1[lane + 192];
        #pragma unroll
        for (int zz = 0; zz < KSPLIT; ++zz) {
            const float* __restrict__ p = part + (size_t)zz * NROWS * HID + off;
            x0 += p[lane]; x1 += p[lane + 64]; x2 += p[lane + 128]; x3 += p[lane + 192];
        }
        const float ga0 = g1[lane], ga1 = g1[lane + 64], ga2 = g1[lane + 128], ga3 = g1[lane + 192];
        const float bb0 = be1[lane], bb1 = be1[lane + 64], bb2 = be1[lane + 128], bb3 = be1[lane + 192];
        const float s  = wave_reduce_sum(x0 + x1 + x2 + x3);
        const float mu = s * (1.0f / 256.0f);
        const float d0 = x0 - mu, d1 = x1 - mu, d2 = x2 - mu, d3 = x3 - mu;
        const float sq = wave_reduce_sum(d0 * d0 + d1 * d1 + d2 * d2 + d3 * d3);
        const float rstd = 1.0f / sqrtf(sq * (1.0f / 256.0f) + EPS_LN);
        h1[wave][lane]       = fmaxf(0.0f, fmaf(d0 * rstd, ga0, bb0));
        h1[wave][lane + 64]  = fmaxf(0.0f, fmaf(d1 * rstd, ga1, bb1));
        h1[wave][lane + 128] = fmaxf(0.0f, fmaf(d2 * rstd, ga2, bb2));
        h1[wave][lane + 192] = fmaxf(0.0f, fmaf(d3 * rstd, ga3, bb3));
    }
    __syncthreads();

    // ---- Stage 2: wave = row, lane = 4 cols; b128 broadcasts + float4 W2 ----
    {
        const int cc = lane << 2;
        float4 acc = *(const float4*)&b2[cc];
        #pragma unroll 4
        for (int k = 0; k < HID; k += 4) {
            const float4 hk = *(const float4*)&h1[wave][k];
            const float4 w0 = *(const float4*)&W2[(size_t)(k + 0) * HID + cc];
            const float4 w1 = *(const float4*)&W2[(size_t)(k + 1) * HID + cc];
            const float4 w2 = *(const float4*)&W2[(size_t)(k + 2) * HID + cc];
            const float4 w3 = *(const float4*)&W2[(size_t)(k + 3) * HID + cc];
            FMA4(acc, hk.x, w0); FMA4(acc, hk.y, w1); FMA4(acc, hk.z, w2); FMA4(acc, hk.w, w3);
        }
        *(float4*)&h2[wave][cc] = acc;
    }
    __syncthreads();

    // ---- LN2 + ReLU (wave per row, in place) ----
    {
        float x0 = h2[wave][lane], x1 = h2[wave][lane + 64], x2 = h2[wave][lane + 128], x3 = h2[wave][lane + 192];
        const float ga0 = g2[lane], ga1 = g2[lane + 64], ga2 = g2[lane + 128], ga3 = g2[lane + 192];
        const float bb0 = be2[lane], bb1 = be2[lane + 64], bb2 = be2[lane + 128], bb3 = be2[lane + 192];
        const float s  = wave_reduce_sum(x0 + x1 + x2 + x3);
        const float mu = s * (1.0f / 256.0f);
        const float d0 = x0 - mu, d1 = x1 - mu, d2 = x2 - mu, d3 = x3 - mu;
        const float sq = wave_reduce_sum(d0 * d0 + d1 * d1 + d2 * d2 + d3 * d3);
        const float rstd = 1.0f / sqrtf(sq * (1.0f / 256.0f) + EPS_LN);
        h2[wave][lane]       = fmaxf(0.0f, fmaf(d0 * rstd, ga0, bb0));
        h2[wave][lane + 64]  = fmaxf(0.0f, fmaf(d1 * rstd, ga1, bb1));
        h2[wave][lane + 128] = fmaxf(0.0f, fmaf(d2 * rstd, ga2, bb2));
        h2[wave][lane + 192] = fmaxf(0.0f, fmaf(d3 * rstd, ga3, bb3));
    }
    __syncthreads();

    // ---- Stage 3: h2(256) @ W3 -> 14 ----
    if (tid < 4 * 14) {
        const int r = tid / 14;
        const int m = tid % 14;
        float a = b3[m];
        #pragma unroll 4
        for (int k = 0; k < HID; ++k) a = fmaf(h2[r][k], W3[k * 14 + m], a);
        raws[r][m] = a;
    }
    __syncthreads();

    // ---- Postprocess + store ----
    if (tid < 4 * 14) {
        const int r = tid / 14;
        const int m = tid % 14;
        const float x = raws[r][m];
        float v;
        if (m < 3) {
            v = x;                                        // pos
        } else if (m < 6) {
            v = fminf(fmaxf(x, 0.0f), 1.0f);              // color clip
        } else if (m == 6) {
            v = 1.0f / (1.0f + expf(-x));                 // opacity sigmoid
        } else if (m < 10) {
            v = expf(x);                                  // scale exp
        } else {
            const float q0 = raws[r][10], q1 = raws[r][11];
            const float q2 = raws[r][12], q3 = raws[r][13];
            const float nrm = sqrtf(q0 * q0 + q1 * q1 + q2 * q2 + q3 * q3);
            v = x / fmaxf(nrm, EPS_NORM);                 // quat normalize
        }
        decoded[(size_t)(blockIdx.x * 4 + r) * 14 + m] = v;
    }
}

// One thread per OUTPUT FLOAT -> perfectly coalesced stores.
__global__ __launch_bounds__(256) void gather_kernel(
    const int* __restrict__ ids,        // (2, N) flat
    const float* __restrict__ decoded,  // (1024, 14)
    float* __restrict__ out,            // (2, N*14) flat
    int N, int total14)
{
    const int j = blockIdx.x * blockDim.x + threadIdx.x;
    if (j >= total14) return;
    const int i = j / 14;               // flat (b,n) point index
    const int k = j - i * 14;           // component 0..13
    const int b = (i >= N) ? 1 : 0;
    const int t = ids[i];               // L1-cached: 14 consecutive lanes share i
    out[j] = decoded[(size_t)(b * TT + t) * 14 + k];
}

extern "C" void kernel_launch(void* const* d_in, const int* in_sizes, int n_in,
                              void* d_out, int out_size, void* d_ws, size_t ws_size,
                              hipStream_t stream) {
    const float* tokens  = (const float*)d_in[0];
    const float* anchors = (const float*)d_in[1];
    const int*   ids     = (const int*)d_in[2];
    const float* W1  = (const float*)d_in[3];
    const float* b1  = (const float*)d_in[4];
    const float* g1  = (const float*)d_in[5];
    const float* be1 = (const float*)d_in[6];
    const float* W2  = (const float*)d_in[7];
    const float* b2  = (const float*)d_in[8];
    const float* g2  = (const float*)d_in[9];
    const float* be2 = (const float*)d_in[10];
    const float* W3  = (const float*)d_in[11];
    const float* b3  = (const float*)d_in[12];

    // decoded (57 KB) in d_ws. Partials (KSPLIT*1024*256*4 = 4,194,304 B) live in
    // d_out (4,480,000 B) — always fits; written by S1, read by S2, then fully
    // overwritten by gather (stream-ordered, no overlap within any kernel).
    float* decoded = (float*)d_ws;
    float* part    = (float*)d_out;
    float* out     = (float*)d_out;

    const int N = in_sizes[2] / NBATCH;           // 40000

    stage1_partial_kernel<<<64 * KSPLIT, 512, 0, stream>>>(tokens, anchors, W1, part);

    decode_tail_kernel<<<NROWS / 4, 256, 0, stream>>>(
        part, b1, g1, be1, W2, b2, g2, be2, W3, b3, decoded);

    const int total14 = NBATCH * N * 14;
    gather_kernel<<<(total14 + 255) / 256, 256, 0, stream>>>(ids, decoded, out, N, total14);
}